// Round 1
// 554.726 us; speedup vs baseline: 1.0103x; 1.0103x over previous
//
#include <hip/hip_runtime.h>
#include <math.h>

// LIF over T=4 steps, elementwise over B*N. T innermost & contiguous:
// one float4 from x + one from lateral per (b,n) group, 4-step recurrence
// in registers, one float4 out. Pure streaming, zero reuse ->
// nontemporal loads/stores.
// Logical traffic 768 MiB; 6.3 TB/s ceiling -> ~122-128 us kernel floor.
//
// This revision: (a) wave-uniform full-tile fast path (no per-item
// predication -> unconditional batched loads, no exec-mask churn),
// (b) persistent capped grid (2048 blocks, grid-stride over tiles) to
// avoid the 16384-block launch/ramp and keep CUs uniformly saturated.

#define TAU 0.25f
#define ITEMS 4
#define BLOCK 256
#define MAX_BLOCKS 2048

typedef float v4f __attribute__((ext_vector_type(4)));

__device__ __forceinline__ void lif_step4(const v4f& xv, const v4f& lv,
                                          float thre, v4f& ov)
{
    float u = 0.0f;
    float o = 0.0f;
#pragma unroll
    for (int t = 0; t < 4; ++t) {
        // reset = 1 - (o_prev > thre); u = TAU*u*reset + x + l
        float acc = xv[t] + lv[t];
        u = (o > thre) ? acc : fmaf(TAU, u, acc);
        // spike forward: o = u if u > thre else 0
        o = (u > thre) ? u : 0.0f;
        ov[t] = o;
    }
}

__global__ __launch_bounds__(BLOCK) void lif_kernel(
    const v4f* __restrict__ x,
    const v4f* __restrict__ lat,
    const float* __restrict__ w,
    v4f* __restrict__ out,
    int n4, int ntiles)
{
    const float thre = tanhf(*w);
    const int tile_sz = BLOCK * ITEMS;

    for (int tile = blockIdx.x; tile < ntiles; tile += gridDim.x) {
        int base = tile * tile_sz + threadIdx.x;

        if (tile * tile_sz + tile_sz <= n4) {
            // Full tile: unconditional, fully batched loads.
            v4f xv[ITEMS], lv[ITEMS];
#pragma unroll
            for (int k = 0; k < ITEMS; ++k) {
                xv[k] = __builtin_nontemporal_load(&x[base + k * BLOCK]);
                lv[k] = __builtin_nontemporal_load(&lat[base + k * BLOCK]);
            }
#pragma unroll
            for (int k = 0; k < ITEMS; ++k) {
                v4f ov;
                lif_step4(xv[k], lv[k], thre, ov);
                __builtin_nontemporal_store(ov, &out[base + k * BLOCK]);
            }
        } else {
            // Tail tile: predicated (never taken for the bench shape).
#pragma unroll
            for (int k = 0; k < ITEMS; ++k) {
                int idx = base + k * BLOCK;
                if (idx >= n4) continue;
                v4f xv = __builtin_nontemporal_load(&x[idx]);
                v4f lv = __builtin_nontemporal_load(&lat[idx]);
                v4f ov;
                lif_step4(xv, lv, thre, ov);
                __builtin_nontemporal_store(ov, &out[idx]);
            }
        }
    }
}

extern "C" void kernel_launch(void* const* d_in, const int* in_sizes, int n_in,
                              void* d_out, int out_size, void* d_ws, size_t ws_size,
                              hipStream_t stream)
{
    const float* x   = (const float*)d_in[0];
    const float* lat = (const float*)d_in[1];
    const float* w   = (const float*)d_in[2];
    float* out       = (float*)d_out;

    int n4 = in_sizes[0] / 4;  // (b,n) groups; T=4 packed per float4

    int tile_sz = BLOCK * ITEMS;
    int ntiles = (n4 + tile_sz - 1) / tile_sz;
    int grid = ntiles < MAX_BLOCKS ? ntiles : MAX_BLOCKS;
    lif_kernel<<<grid, BLOCK, 0, stream>>>(
        (const v4f*)x, (const v4f*)lat, w, (v4f*)out, n4, ntiles);
}